// Round 3
// baseline (422.519 us; speedup 1.0000x reference)
//
#include <hip/hip_runtime.h>
#include <stdint.h>

// W8A8B32O32 Linear: Y[m,n] = round(out_scale * sum_k X[m,k]*W[n,k] + bias_scale * bias[n])
// HARNESS NOTE: integer inputs are materialized as int32 arrays ("integer -> const int*"),
// so the int8-valued x/weight arrive as int32. Round 3: pack int32->int8 into d_ws
// (exact: values in [-127,127)), then run the m97-style DMA-staged i8 MFMA GEMM.
// Rounds 1&2 produced bit-identical output via two staging paths -> staging/layout
// machinery is self-consistent; the dtype cast was the bug.

typedef int v4i __attribute__((ext_vector_type(4)));

#define BM 128
#define BN 128
#define BK 64
#define KK 4096

// ---------------- pack: int32 -> int8 (truncate low byte) ----------------
__global__ __launch_bounds__(256)
void pack_i32_to_i8(const int* __restrict__ src, int8_t* __restrict__ dst, int n16) {
    int i = blockIdx.x * blockDim.x + threadIdx.x;   // one thread = 16 elements
    if (i >= n16) return;
    const v4i* s4 = (const v4i*)src;
    v4i out;
#pragma unroll
    for (int q = 0; q < 4; q++) {
        v4i a = s4[i * 4 + q];
        out[q] = (a[0] & 0xff) | ((a[1] & 0xff) << 8) | ((a[2] & 0xff) << 16) | (a[3] << 24);
    }
    *(v4i*)(dst + (size_t)i * 16) = out;
}

// ---------------- GEMM ----------------
__device__ __forceinline__ void gld_lds16(const void* g, void* lds) {
    __builtin_amdgcn_global_load_lds(
        (const __attribute__((address_space(1))) unsigned int*)g,
        (__attribute__((address_space(3))) unsigned int*)lds,
        16, 0, 0);
}

__global__ __launch_bounds__(256, 2)
void w8a8_gemm_kernel(const int8_t* __restrict__ X,
                      const int8_t* __restrict__ W,
                      const int*    __restrict__ bias,
                      const float*  __restrict__ out_scale_p,
                      const float*  __restrict__ bias_scale_p,
                      int*          __restrict__ Y,
                      int M, int N)
{
    __shared__ __align__(16) int8_t sA[BM * BK];  // 8 KB row-major [m][k], 64 B rows
    __shared__ __align__(16) int8_t sB[BN * BK];  // 8 KB row-major [n][k]

    const int t = threadIdx.x;
    const int w = t >> 6;
    const int l = t & 63;
    const int wm = w >> 1;       // wave row in 2x2
    const int wn = w & 1;        // wave col

    const int bn = blockIdx.x * BN;
    const int bm = blockIdx.y * BM;

    const float out_scale  = *out_scale_p;
    const float bias_scale = *bias_scale_p;

    const int8_t* Abase = X + (size_t)bm * KK;
    const int8_t* Bbase = W + (size_t)bn * KK;

    // Staging: tile = 512 chunks of 16 B (128 rows x 4 chunks/row). Two DMA rounds
    // of 256 chunks; within a round, wave-uniform LDS base + lane*16 (m104/m108 rule).
    // chunk c = round*256 + w*64 + l -> LDS byte c*16, global (c>>2)*K + (c&3)*16.
    const int c0 = w * 64 + l;
    const int c1 = 256 + c0;
    const int ga0 = (c0 >> 2) * KK + (c0 & 3) * 16;
    const int ga1 = (c1 >> 2) * KK + (c1 & 3) * 16;

    int8_t* sA_r0 = sA + w * 1024;
    int8_t* sA_r1 = sA + 4096 + w * 1024;
    int8_t* sB_r0 = sB + w * 1024;
    int8_t* sB_r1 = sB + 4096 + w * 1024;

    // Fragment addresses: lane holds A[m=lane&15][k = quad*16 + j] (16 contiguous bytes).
    const int tm   = l & 15;
    const int quad = l >> 4;
    const int ldsA = (wm * 64 + tm) * BK + quad * 16;
    const int ldsB = (wn * 64 + tm) * BK + quad * 16;

    v4i acc[4][4];
    const v4i vzero = {0, 0, 0, 0};
#pragma unroll
    for (int i = 0; i < 4; i++)
#pragma unroll
        for (int j = 0; j < 4; j++)
            acc[i][j] = vzero;

    for (int k0 = 0; k0 < KK; k0 += BK) {
        gld_lds16(Abase + ga0 + k0, sA_r0);
        gld_lds16(Abase + ga1 + k0, sA_r1);
        gld_lds16(Bbase + ga0 + k0, sB_r0);
        gld_lds16(Bbase + ga1 + k0, sB_r1);
        __syncthreads();   // drains vmcnt (global_load_lds) + barrier

        v4i a[4], b[4];
#pragma unroll
        for (int i = 0; i < 4; i++)
            a[i] = *(const v4i*)(sA + ldsA + i * 16 * BK);
#pragma unroll
        for (int j = 0; j < 4; j++)
            b[j] = *(const v4i*)(sB + ldsB + j * 16 * BK);

#pragma unroll
        for (int i = 0; i < 4; i++)
#pragma unroll
            for (int j = 0; j < 4; j++)
                acc[i][j] = __builtin_amdgcn_mfma_i32_16x16x64_i8(a[i], b[j], acc[i][j], 0, 0, 0);

        __syncthreads();   // frag reads done before next overwrite
    }

    // Epilogue. C/D layout: col(n)=lane&15, row(m)=quad*4+reg.
#pragma unroll
    for (int j = 0; j < 4; j++) {
        const int n = bn + wn * 64 + j * 16 + tm;
        const float bb = (float)bias[n] * bias_scale;
#pragma unroll
        for (int i = 0; i < 4; i++) {
            const int mb = bm + wm * 64 + i * 16 + quad * 4;
#pragma unroll
            for (int r = 0; r < 4; r++) {
                const float v = (float)acc[i][j][r] * out_scale + bb;
                Y[(size_t)(mb + r) * N + n] = (int)rintf(v);
            }
        }
    }
}

extern "C" void kernel_launch(void* const* d_in, const int* in_sizes, int n_in,
                              void* d_out, int out_size, void* d_ws, size_t ws_size,
                              hipStream_t stream) {
    const int* x32 = (const int*)d_in[0];   // int8 values stored as int32
    const int* w32 = (const int*)d_in[1];
    const int*    bias = (const int*)d_in[2];
    const float*  os   = (const float*)d_in[3];
    const float*  bs   = (const float*)d_in[4];
    int* out = (int*)d_out;

    const int K = KK;
    const int M = in_sizes[0] / K;   // 8192
    const int N = in_sizes[1] / K;   // 4096
    const int nx = in_sizes[0];      // 33554432
    const int nw = in_sizes[1];      // 16777216

    int8_t* x8 = (int8_t*)d_ws;              // 33.5 MB
    int8_t* w8 = x8 + (size_t)nx;            // 16.8 MB  (total 50.3 MB < ws_size)

    pack_i32_to_i8<<<dim3(nx / 16 / 256), dim3(256), 0, stream>>>(x32, x8, nx / 16);
    pack_i32_to_i8<<<dim3(nw / 16 / 256), dim3(256), 0, stream>>>(w32, w8, nw / 16);

    dim3 grid(N / BN, M / BM);       // (32, 64)
    dim3 block(256);
    hipLaunchKernelGGL(w8a8_gemm_kernel, grid, block, 0, stream,
                       x8, w8, bias, os, bs, out, M, N);
}

// Round 4
// 421.278 us; speedup vs baseline: 1.0029x; 1.0029x over previous
//
#include <hip/hip_runtime.h>
#include <stdint.h>

// W8A8B32O32 Linear: Y[m,n] = round(out_scale * sum_k X[m,k]*W[n,k] + bias_scale * bias[n])
// Harness materializes integer inputs as int32; pre-pass packs int32->int8 into d_ws
// (exact for values in [-127,127)), then m97-style DMA-staged mfma_i32_16x16x64_i8 GEMM.
// Round 4: coalesced pack (lane i: int4 load @16B/lane contiguous -> 1 packed dword out).
// Round-3 pack had 64B inter-lane stride -> 6x off HBM roofline (240us vs 40us floor).

typedef int v4i __attribute__((ext_vector_type(4)));

#define BM 128
#define BN 128
#define BK 64
#define KK 4096

// ---------------- pack: 4x int32 -> 4x int8 in one dword ----------------
__global__ __launch_bounds__(256)
void pack_i32_to_i8(const v4i* __restrict__ src, int* __restrict__ dst, int n4) {
    int i = blockIdx.x * blockDim.x + threadIdx.x;   // one thread = 4 elements
    if (i >= n4) return;
    v4i a = src[i];   // 16 B/lane, consecutive lanes contiguous -> coalesced
    dst[i] = (a[0] & 0xff) | ((a[1] & 0xff) << 8) | ((a[2] & 0xff) << 16) | (a[3] << 24);
}

// ---------------- GEMM (unchanged from round 3: 39% of i8 ceiling) ----------------
__device__ __forceinline__ void gld_lds16(const void* g, void* lds) {
    __builtin_amdgcn_global_load_lds(
        (const __attribute__((address_space(1))) unsigned int*)g,
        (__attribute__((address_space(3))) unsigned int*)lds,
        16, 0, 0);
}

__global__ __launch_bounds__(256, 2)
void w8a8_gemm_kernel(const int8_t* __restrict__ X,
                      const int8_t* __restrict__ W,
                      const int*    __restrict__ bias,
                      const float*  __restrict__ out_scale_p,
                      const float*  __restrict__ bias_scale_p,
                      int*          __restrict__ Y,
                      int M, int N)
{
    __shared__ __align__(16) int8_t sA[BM * BK];  // 8 KB row-major [m][k], 64 B rows
    __shared__ __align__(16) int8_t sB[BN * BK];  // 8 KB row-major [n][k]

    const int t = threadIdx.x;
    const int w = t >> 6;
    const int l = t & 63;
    const int wm = w >> 1;       // wave row in 2x2
    const int wn = w & 1;        // wave col

    const int bn = blockIdx.x * BN;
    const int bm = blockIdx.y * BM;

    const float out_scale  = *out_scale_p;
    const float bias_scale = *bias_scale_p;

    const int8_t* Abase = X + (size_t)bm * KK;
    const int8_t* Bbase = W + (size_t)bn * KK;

    // Staging: tile = 512 chunks of 16 B (128 rows x 4 chunks/row). Two DMA rounds
    // of 256 chunks; wave-uniform LDS base + lane*16 (m104/m108 rule).
    const int c0 = w * 64 + l;
    const int c1 = 256 + c0;
    const int ga0 = (c0 >> 2) * KK + (c0 & 3) * 16;
    const int ga1 = (c1 >> 2) * KK + (c1 & 3) * 16;

    int8_t* sA_r0 = sA + w * 1024;
    int8_t* sA_r1 = sA + 4096 + w * 1024;
    int8_t* sB_r0 = sB + w * 1024;
    int8_t* sB_r1 = sB + 4096 + w * 1024;

    // Fragment addresses: lane holds A[m=lane&15][k = quad*16 + j] (16 contiguous bytes).
    const int tm   = l & 15;
    const int quad = l >> 4;
    const int ldsA = (wm * 64 + tm) * BK + quad * 16;
    const int ldsB = (wn * 64 + tm) * BK + quad * 16;

    v4i acc[4][4];
    const v4i vzero = {0, 0, 0, 0};
#pragma unroll
    for (int i = 0; i < 4; i++)
#pragma unroll
        for (int j = 0; j < 4; j++)
            acc[i][j] = vzero;

    for (int k0 = 0; k0 < KK; k0 += BK) {
        gld_lds16(Abase + ga0 + k0, sA_r0);
        gld_lds16(Abase + ga1 + k0, sA_r1);
        gld_lds16(Bbase + ga0 + k0, sB_r0);
        gld_lds16(Bbase + ga1 + k0, sB_r1);
        __syncthreads();   // drains vmcnt (global_load_lds) + barrier

        v4i a[4], b[4];
#pragma unroll
        for (int i = 0; i < 4; i++)
            a[i] = *(const v4i*)(sA + ldsA + i * 16 * BK);
#pragma unroll
        for (int j = 0; j < 4; j++)
            b[j] = *(const v4i*)(sB + ldsB + j * 16 * BK);

#pragma unroll
        for (int i = 0; i < 4; i++)
#pragma unroll
            for (int j = 0; j < 4; j++)
                acc[i][j] = __builtin_amdgcn_mfma_i32_16x16x64_i8(a[i], b[j], acc[i][j], 0, 0, 0);

        __syncthreads();   // frag reads done before next overwrite
    }

    // Epilogue. C/D layout: col(n)=lane&15, row(m)=quad*4+reg.
#pragma unroll
    for (int j = 0; j < 4; j++) {
        const int n = bn + wn * 64 + j * 16 + tm;
        const float bb = (float)bias[n] * bias_scale;
#pragma unroll
        for (int i = 0; i < 4; i++) {
            const int mb = bm + wm * 64 + i * 16 + quad * 4;
#pragma unroll
            for (int r = 0; r < 4; r++) {
                const float v = (float)acc[i][j][r] * out_scale + bb;
                Y[(size_t)(mb + r) * N + n] = (int)rintf(v);
            }
        }
    }
}

extern "C" void kernel_launch(void* const* d_in, const int* in_sizes, int n_in,
                              void* d_out, int out_size, void* d_ws, size_t ws_size,
                              hipStream_t stream) {
    const int* x32 = (const int*)d_in[0];   // int8 values stored as int32
    const int* w32 = (const int*)d_in[1];
    const int*    bias = (const int*)d_in[2];
    const float*  os   = (const float*)d_in[3];
    const float*  bs   = (const float*)d_in[4];
    int* out = (int*)d_out;

    const int K = KK;
    const int M = in_sizes[0] / K;   // 8192
    const int N = in_sizes[1] / K;   // 4096
    const int nx = in_sizes[0];      // 33554432
    const int nw = in_sizes[1];      // 16777216

    int8_t* x8 = (int8_t*)d_ws;              // 33.5 MB
    int8_t* w8 = x8 + (size_t)nx;            // 16.8 MB  (total 50.3 MB < ws_size)

    pack_i32_to_i8<<<dim3(nx / 4 / 256), dim3(256), 0, stream>>>((const v4i*)x32, (int*)x8, nx / 4);
    pack_i32_to_i8<<<dim3(nw / 4 / 256), dim3(256), 0, stream>>>((const v4i*)w32, (int*)w8, nw / 4);

    dim3 grid(N / BN, M / BM);       // (32, 64)
    dim3 block(256);
    hipLaunchKernelGGL(w8a8_gemm_kernel, grid, block, 0, stream,
                       x8, w8, bias, os, bs, out, M, N);
}

// Round 5
// 387.077 us; speedup vs baseline: 1.0916x; 1.0884x over previous
//
#include <hip/hip_runtime.h>
#include <stdint.h>

// W8A8B32O32 Linear: Y[m,n] = round(out_scale * sum_k X[m,k]*W[n,k] + bias_scale * bias[n])
// Harness materializes integer inputs as int32 -> pre-pass packs to int8 in d_ws (exact),
// then DMA-staged mfma_i32_16x16x64_i8 GEMM, 128x128 tile, 4 waves 2x2.
// Round 5: BK=128 (halves barrier-drain count; D~600cyc/iter was ~50% of GEMM time)
// + XOR bank swizzle (chunk q of row r at slot q^(r&7); kills the 8/16-way ds_read_b128
// conflicts, SQ_LDS_BANK_CONFLICT=1.678e7 = ~15% of runtime). NOTE: per-replay dur_us
// includes ~200us fixed harness restore/poison (10 dispatches/replay); GEMM is the lever.

typedef int v4i __attribute__((ext_vector_type(4)));

#define BM 128
#define BN 128
#define BK 128
#define KK 4096

// ---------------- pack: 4x int32 -> 4x int8 in one dword (coalesced, ~roofline) ----------------
__global__ __launch_bounds__(256)
void pack_i32_to_i8(const v4i* __restrict__ src, int* __restrict__ dst, int n4) {
    int i = blockIdx.x * blockDim.x + threadIdx.x;   // one thread = 4 elements
    if (i >= n4) return;
    v4i a = src[i];
    dst[i] = (a[0] & 0xff) | ((a[1] & 0xff) << 8) | ((a[2] & 0xff) << 16) | (a[3] << 24);
}

// ---------------- GEMM ----------------
__device__ __forceinline__ void gld_lds16(const void* g, void* lds) {
    __builtin_amdgcn_global_load_lds(
        (const __attribute__((address_space(1))) unsigned int*)g,
        (__attribute__((address_space(3))) unsigned int*)lds,
        16, 0, 0);
}

__global__ __launch_bounds__(256, 2)
void w8a8_gemm_kernel(const int8_t* __restrict__ X,
                      const int8_t* __restrict__ W,
                      const int*    __restrict__ bias,
                      const float*  __restrict__ out_scale_p,
                      const float*  __restrict__ bias_scale_p,
                      int*          __restrict__ Y,
                      int M, int N)
{
    __shared__ __align__(16) int8_t sA[BM * BK];  // 16 KB, rows of 128 B, XOR-swizzled chunks
    __shared__ __align__(16) int8_t sB[BN * BK];  // 16 KB

    const int t = threadIdx.x;
    const int w = t >> 6;
    const int l = t & 63;
    const int wm = w >> 1;       // wave row in 2x2
    const int wn = w & 1;        // wave col

    const int bn = blockIdx.x * BN;
    const int bm = blockIdx.y * BM;

    const float out_scale  = *out_scale_p;
    const float bias_scale = *bias_scale_p;

    const int8_t* Abase = X + (size_t)bm * KK;
    const int8_t* Bbase = W + (size_t)bn * KK;

    // Staging: per matrix 1024 chunks of 16 B (128 rows x 8 chunks). 4 DMA rounds of 256.
    // LDS slot c (= r*256 + w*64 + l, byte c*16, wave-uniform base + lane*16) holds global
    // chunk (c&7) ^ ((c>>3)&7) of row c>>3  -> XOR swizzle via SOURCE address permutation.
    int ga[4];
#pragma unroll
    for (int r = 0; r < 4; r++) {
        const int c   = r * 256 + w * 64 + l;
        const int row = c >> 3;
        const int j   = c & 7;
        ga[r] = row * KK + ((j ^ (row & 7)) << 4);
    }

    // Fragment addresses: lane (tm,quad) reads A[m=tm][k = h*64 + quad*16 + jj], i.e.
    // chunk q = h*4+quad of row m -> LDS slot q ^ (row&7), row&7 == tm&7.
    const int tm   = l & 15;
    const int quad = l >> 4;
    const int s3   = tm & 7;
    const int rowA = (wm * 64 + tm) * BK;   // byte base of A row (i-tile adds i*16*BK)
    const int rowB = (wn * 64 + tm) * BK;

    v4i acc[4][4];
    const v4i vzero = {0, 0, 0, 0};
#pragma unroll
    for (int i = 0; i < 4; i++)
#pragma unroll
        for (int j = 0; j < 4; j++)
            acc[i][j] = vzero;

    for (int k0 = 0; k0 < KK; k0 += BK) {
#pragma unroll
        for (int r = 0; r < 4; r++) {
            gld_lds16(Abase + ga[r] + k0, sA + r * 4096 + w * 1024);
            gld_lds16(Bbase + ga[r] + k0, sB + r * 4096 + w * 1024);
        }
        __syncthreads();   // drains vmcnt (DMA) + publishes tile

#pragma unroll
        for (int h = 0; h < 2; h++) {
            const int xo = (((h << 2) + quad) ^ s3) << 4;   // swizzled in-row byte offset
            v4i a[4], b[4];
#pragma unroll
            for (int i = 0; i < 4; i++)
                a[i] = *(const v4i*)(sA + rowA + i * 16 * BK + xo);
#pragma unroll
            for (int j = 0; j < 4; j++)
                b[j] = *(const v4i*)(sB + rowB + j * 16 * BK + xo);
#pragma unroll
            for (int i = 0; i < 4; i++)
#pragma unroll
                for (int j = 0; j < 4; j++)
                    acc[i][j] = __builtin_amdgcn_mfma_i32_16x16x64_i8(a[i], b[j], acc[i][j], 0, 0, 0);
        }

        __syncthreads();   // frag reads done before next overwrite
    }

    // Epilogue. C/D layout: col(n)=lane&15, row(m)=quad*4+reg.
#pragma unroll
    for (int j = 0; j < 4; j++) {
        const int n = bn + wn * 64 + j * 16 + tm;
        const float bb = (float)bias[n] * bias_scale;
#pragma unroll
        for (int i = 0; i < 4; i++) {
            const int mb = bm + wm * 64 + i * 16 + quad * 4;
#pragma unroll
            for (int r = 0; r < 4; r++) {
                const float v = (float)acc[i][j][r] * out_scale + bb;
                Y[(size_t)(mb + r) * N + n] = (int)rintf(v);
            }
        }
    }
}

extern "C" void kernel_launch(void* const* d_in, const int* in_sizes, int n_in,
                              void* d_out, int out_size, void* d_ws, size_t ws_size,
                              hipStream_t stream) {
    const int* x32 = (const int*)d_in[0];   // int8 values stored as int32
    const int* w32 = (const int*)d_in[1];
    const int*    bias = (const int*)d_in[2];
    const float*  os   = (const float*)d_in[3];
    const float*  bs   = (const float*)d_in[4];
    int* out = (int*)d_out;

    const int K = KK;
    const int M = in_sizes[0] / K;   // 8192
    const int N = in_sizes[1] / K;   // 4096
    const int nx = in_sizes[0];      // 33554432
    const int nw = in_sizes[1];      // 16777216

    int8_t* x8 = (int8_t*)d_ws;              // 33.5 MB
    int8_t* w8 = x8 + (size_t)nx;            // 16.8 MB  (total 50.3 MB < ws_size)

    pack_i32_to_i8<<<dim3(nx / 4 / 256), dim3(256), 0, stream>>>((const v4i*)x32, (int*)x8, nx / 4);
    pack_i32_to_i8<<<dim3(nw / 4 / 256), dim3(256), 0, stream>>>((const v4i*)w32, (int*)w8, nw / 4);

    dim3 grid(N / BN, M / BM);       // (32, 64)
    dim3 block(256);
    hipLaunchKernelGGL(w8a8_gemm_kernel, grid, block, 0, stream,
                       x8, w8, bias, os, bs, out, M, N);
}